// Round 3
// baseline (28005.008 us; speedup 1.0000x reference)
//
#include <hip/hip_runtime.h>
#include <stdint.h>

// 2-layer masked GRU encoder, B=64 T=512 D=U=512. float32 in/out, mask=int32.
// 256 WGs lockstep: even WGs (pipe A) = layer 0 at phase s, odd WGs (pipe B) =
// layer 1 at phase s-1. One global flag-barrier per phase. bf16 MFMA compute.
// Scratch: h0[2][64][512]f32 | h1[2][64][512]f32 | h0n[2][64][512]bf16
//          | flags[513][256]u32  == 1,180,672 bytes.

#define TT 512

typedef __attribute__((ext_vector_type(8))) short bfrag_t;   // 8 x bf16
typedef __attribute__((ext_vector_type(4))) float f32x4;

__device__ inline unsigned short f2bf(float f) {
  unsigned u = __float_as_uint(f);
  unsigned r = u + 0x7FFFu + ((u >> 16) & 1u);   // RNE
  return (unsigned short)(r >> 16);
}
__device__ inline unsigned pack2(float lo, float hi) {
  return (unsigned)f2bf(lo) | ((unsigned)f2bf(hi) << 16);
}
__device__ inline float sigmoidf_(float x) { return 1.0f / (1.0f + __expf(-x)); }
__device__ inline float fast_tanh(float x) {
  float ax = fabsf(x);
  float e = __expf(-2.0f * ax);
  float t = (1.0f - e) / (1.0f + e);
  return x < 0.0f ? -t : t;
}

// Whole wave: wait until all 256 flags == expect (4 per lane).
__device__ inline void spin256(const unsigned* f, unsigned expect) {
  const int lane = threadIdx.x & 63;
  const unsigned* p = f + 4 * lane;
  for (;;) {
    unsigned a = __hip_atomic_load(p,     __ATOMIC_ACQUIRE, __HIP_MEMORY_SCOPE_AGENT);
    unsigned b = __hip_atomic_load(p + 1, __ATOMIC_ACQUIRE, __HIP_MEMORY_SCOPE_AGENT);
    unsigned c = __hip_atomic_load(p + 2, __ATOMIC_ACQUIRE, __HIP_MEMORY_SCOPE_AGENT);
    unsigned d = __hip_atomic_load(p + 3, __ATOMIC_ACQUIRE, __HIP_MEMORY_SCOPE_AGENT);
    if (__ballot((a == expect) && (b == expect) && (c == expect) && (d == expect))
        == 0xFFFFFFFFFFFFFFFFull) break;
  }
}

extern "C" __global__ void __launch_bounds__(256, 1)
gru2_lockstep(const float* __restrict__ x,     // [64][512][512] f32
              const int*   __restrict__ mask,  // [64][512] i32
              const float* __restrict__ W0,    // [512][1536] f32
              const float* __restrict__ U0,
              const float* __restrict__ b0,    // [2][1536]
              const float* __restrict__ W1,
              const float* __restrict__ U1,
              const float* __restrict__ b1,
              float* __restrict__ out,         // [16777216 + 2*32768] f32
              unsigned char* __restrict__ ws)
{
  extern __shared__ unsigned short sm[];
  unsigned short* wt  = sm;               // [96][520] bf16 transposed weights
  unsigned short* st0 = sm + 96 * 520;    // [16][520] input operand (x or h0n)
  unsigned short* st1 = st0 + 16 * 520;   // [16][520] hidden operand
  float* accs = (float*)(st1 + 16 * 520); // [4][256]

  float* h0buf = (float*)ws;                               // [2][64][512] f32
  float* h1buf = h0buf + 65536;
  unsigned short* h0n = (unsigned short*)(ws + 524288);    // [2][64][512] bf16
  unsigned* flags = (unsigned*)(ws + 655360);              // [513][256] u32

  const int tid  = threadIdx.x;
  const int wg   = blockIdx.x;
  const int pipe = wg & 1;
  const int idx  = wg >> 1;
  const int mi = idx & 3,  ni = idx >> 2;
  const int r0 = mi * 16,  c0 = ni * 16;
  const int wave = tid >> 6, lane = tid & 63;
  const int quad = lane >> 4, n16 = lane & 15;

  const float* Wm = pipe ? W1 : W0;
  const float* Um = pipe ? U1 : U0;
  const float* bp = pipe ? b1 : b0;
  float* hbuf = pipe ? h1buf : h0buf;

  // ---- one-time: transpose my 48 gate-cols of W and U into LDS bf16 [n][k] ----
  {
    const int col  = tid & 15;
    const int ksub = tid >> 4;
    for (int k0 = 0; k0 < 512; k0 += 16) {
      const int k = k0 + ksub;
      const float* M0 = Wm + (size_t)k * 1536;
      const float* M1 = Um + (size_t)k * 1536;
      #pragma unroll
      for (int g = 0; g < 3; ++g) {
        wt[(g * 16 + col) * 520 + k]      = f2bf(M0[g * 512 + c0 + col]);
        wt[(48 + g * 16 + col) * 520 + k] = f2bf(M1[g * 512 + c0 + col]);
      }
    }
  }
  __syncthreads();

  // wave roles: w0=z (concat x|h), w1=r (concat), w2=ih (x), w3=hh (h)
  const int g  = (wave < 2) ? wave : 2;
  const int np = (wave < 2) ? 2 : 1;

  bfrag_t bw0[16], bw1[16];
  {
    const int mat0 = (wave == 3) ? 1 : 0;
    const int row0 = mat0 * 48 + g * 16 + n16;
    #pragma unroll
    for (int f = 0; f < 16; ++f)
      bw0[f] = *(const bfrag_t*)&wt[row0 * 520 + f * 32 + quad * 8];
    if (np == 2) {
      const int row1 = 48 + g * 16 + n16;
      #pragma unroll
      for (int f = 0; f < 16; ++f)
        bw1[f] = *(const bfrag_t*)&wt[row1 * 520 + f * 32 + quad * 8];
    }
  }

  float bsc;
  {
    const int colg = g * 512 + c0 + n16;
    const float bi = bp[colg];
    const float bh = bp[1536 + colg];
    bsc = (wave < 2) ? (bi + bh) : ((wave == 2) ? bi : bh);
  }

  float oprev = 0.0f;
  const int erow = tid >> 4, ecol = tid & 15;
  const int eb = r0 + erow, ec = c0 + ecol;

  for (int s = 0; s <= TT; ++s) {
    const bool actA = (pipe == 0) && (s < TT);
    const bool actB = (pipe == 1) && (s > 0);
    const bool act  = actA || actB;
    const int  t    = pipe ? (s - 1) : s;

    // ---- barrier wait (wave 0) overlapped with pipe-A x(s) prestage ----
    if (actA && tid >= 128) {
      const int sm2 = (tid - 128) >> 3;     // 0..15 row
      const int sk2 = (tid & 7) * 64;       // 0..448 col
      const float* src = x + (((size_t)(r0 + sm2) * 512 + s) * 512 + sk2);
      uint4* dst = (uint4*)(st0 + sm2 * 520 + sk2);
      #pragma unroll
      for (int c = 0; c < 8; ++c) {
        float4 a = ((const float4*)src)[2 * c];
        float4 b = ((const float4*)src)[2 * c + 1];
        uint4 u;
        u.x = pack2(a.x, a.y);  u.y = pack2(a.z, a.w);
        u.z = pack2(b.x, b.y);  u.w = pack2(b.z, b.w);
        dst[c] = u;
      }
    } else if (wave == 0 && s > 0) {
      spin256(flags + (size_t)(s - 1) * 256, (unsigned)s);
    }
    __syncthreads();
    __threadfence();   // acquire side: make remote h-state / h0n visible

    // ---- stage hidden state (f32 -> bf16); pipe B also stages h0n(t) ----
    if (act) {
      const int smr = tid >> 4;
      const int skk = (tid & 15) * 32;
      const float* hsrc = hbuf + ((t + 1) & 1) * 32768 + (size_t)(r0 + smr) * 512 + skk;
      uint4* dst = (uint4*)(st1 + smr * 520 + skk);
      #pragma unroll
      for (int c = 0; c < 4; ++c) {
        float4 a = ((const float4*)hsrc)[2 * c];
        float4 b = ((const float4*)hsrc)[2 * c + 1];
        uint4 u;
        u.x = pack2(a.x, a.y);  u.y = pack2(a.z, a.w);
        u.z = pack2(b.x, b.y);  u.w = pack2(b.z, b.w);
        dst[c] = u;
      }
      if (pipe == 1) {   // h0n(t) written by pipe A in phase t=s-1, parity t&1
        const uint4* rs = (const uint4*)(h0n + (size_t)(t & 1) * 32768 +
                                         (size_t)(r0 + smr) * 512 + skk);
        uint4* d0 = (uint4*)(st0 + smr * 520 + skk);
        #pragma unroll
        for (int c = 0; c < 4; ++c) d0[c] = rs[c];
      }
    }
    __syncthreads();

    // ---- MFMA ----
    if (act) {
      f32x4 acc = {bsc, bsc, bsc, bsc};
      const unsigned short* s0 = (wave == 3) ? st1 : st0;
      const int abase = n16 * 520 + quad * 8;
      #pragma unroll
      for (int f = 0; f < 16; ++f) {
        bfrag_t a = *(const bfrag_t*)&s0[abase + f * 32];
        acc = __builtin_amdgcn_mfma_f32_16x16x32_bf16(a, bw0[f], acc, 0, 0, 0);
      }
      if (np == 2) {
        #pragma unroll
        for (int f = 0; f < 16; ++f) {
          bfrag_t a = *(const bfrag_t*)&st1[abase + f * 32];
          acc = __builtin_amdgcn_mfma_f32_16x16x32_bf16(a, bw1[f], acc, 0, 0, 0);
        }
      }
      #pragma unroll
      for (int i = 0; i < 4; ++i)
        accs[wave * 256 + (quad * 4 + i) * 16 + n16] = acc[i];  // row=quad*4+i, col=n16
    }
    __syncthreads();

    // ---- elementwise GRU cell ----
    if (act) {
      const float zv = sigmoidf_(accs[0 * 256 + tid]);
      const float rv = sigmoidf_(accs[1 * 256 + tid]);
      const float candv = fast_tanh(accs[2 * 256 + tid] + rv * accs[3 * 256 + tid]);
      const float* hrd = hbuf + ((t + 1) & 1) * 32768;
      float*       hwr = hbuf + (t & 1) * 32768;
      const float hold = hrd[(size_t)eb * 512 + ec];
      const float hn = zv * hold + (1.0f - zv) * candv;
      const bool  m  = mask[(size_t)eb * 512 + t] != 0;
      const float hc = m ? hn : hold;
      hwr[(size_t)eb * 512 + ec] = hc;
      if (pipe == 0) {
        h0n[(size_t)(t & 1) * 32768 + (size_t)eb * 512 + ec] = f2bf(hn);  // UNMASKED
        if (t == TT - 1) out[(size_t)16777216 + (size_t)eb * 512 + ec] = hc;        // h0f
      } else {
        const float ov = m ? hn : oprev;
        oprev = ov;
        out[(size_t)eb * 262144 + (size_t)t * 512 + ec] = ov;                        // output
        if (t == TT - 1) out[(size_t)16777216 + 32768 + (size_t)eb * 512 + ec] = hc; // h1f
      }
    }
    __threadfence();    // release side
    __syncthreads();
    if (tid == 0)
      __hip_atomic_store(&flags[(size_t)s * 256 + wg], (unsigned)(s + 1),
                         __ATOMIC_RELEASE, __HIP_MEMORY_SCOPE_AGENT);
  }
}

extern "C" void kernel_launch(void* const* d_in, const int* in_sizes, int n_in,
                              void* d_out, int out_size, void* d_ws, size_t ws_size,
                              hipStream_t stream) {
  (void)in_sizes; (void)n_in; (void)out_size;
  const float* x    = (const float*)d_in[0];
  const int*   mask = (const int*)  d_in[1];
  const float* W0   = (const float*)d_in[2];
  const float* U0   = (const float*)d_in[3];
  const float* b0   = (const float*)d_in[4];
  const float* W1   = (const float*)d_in[5];
  const float* U1   = (const float*)d_in[6];
  const float* b1   = (const float*)d_in[7];
  float* out = (float*)d_out;
  unsigned char* ws = (unsigned char*)d_ws;

  const size_t need = 1180672;
  const size_t zb = ws_size < need ? ws_size : need;
  hipMemsetAsync(d_ws, 0, zb, stream);

  hipFuncSetAttribute((const void*)gru2_lockstep,
                      hipFuncAttributeMaxDynamicSharedMemorySize, 137216);
  void* args[] = { (void*)&x, (void*)&mask, (void*)&W0, (void*)&U0, (void*)&b0,
                   (void*)&W1, (void*)&U1, (void*)&b1, (void*)&out, (void*)&ws };
  hipLaunchCooperativeKernel((void*)gru2_lockstep, dim3(256), dim3(256),
                             args, 137216, stream);
}

// Round 4
// 2717.549 us; speedup vs baseline: 10.3052x; 10.3052x over previous
//
#include <hip/hip_runtime.h>
#include <stdint.h>

// 2-layer masked GRU encoder, B=64 T=512 D=U=512. f32 in/out, mask=int32.
// 256 WGs lockstep, software-pipelined: even WGs (pipe A) = layer 0 at phase s,
// odd WGs (pipe B) = layer 1 at phase s-1. One flag-barrier per phase.
// All cross-WG data via RELAXED agent-scope atomics (sc1, MALL-coherent) --
// no acquire/release fences => no buffer_inv / buffer_wbl2 L2 tag sweeps.
// fp32 h-carry lives in registers (1 elem/thread); only bf16 h published.
// ws: h0pub[2][64][512]bf16 | h1pub[2][64][512]bf16 | h0n[2][64][512]bf16
//     | flags[513][256]u32   == 918,528 bytes.

#define TT 512

typedef __attribute__((ext_vector_type(8))) short bfrag_t;   // 8 x bf16
typedef __attribute__((ext_vector_type(4))) float f32x4;

__device__ inline unsigned short f2bf(float f) {
  unsigned u = __float_as_uint(f);
  unsigned r = u + 0x7FFFu + ((u >> 16) & 1u);   // RNE
  return (unsigned short)(r >> 16);
}
__device__ inline unsigned pack2(float lo, float hi) {
  return (unsigned)f2bf(lo) | ((unsigned)f2bf(hi) << 16);
}
__device__ inline float sigmoidf_(float x) { return 1.0f / (1.0f + __expf(-x)); }
__device__ inline float fast_tanh(float x) {
  float ax = fabsf(x);
  float e = __expf(-2.0f * ax);
  float t = (1.0f - e) / (1.0f + e);
  return x < 0.0f ? -t : t;
}

__device__ inline void st8(void* p, unsigned long long v) {
  __hip_atomic_store((unsigned long long*)p, v, __ATOMIC_RELAXED, __HIP_MEMORY_SCOPE_AGENT);
}
__device__ inline unsigned long long ld8(const void* p) {
  return __hip_atomic_load((const unsigned long long*)p, __ATOMIC_RELAXED, __HIP_MEMORY_SCOPE_AGENT);
}

// Whole wave: wait until all 256 flags == expect. RELAXED loads only.
__device__ inline void spin256(const unsigned* f, unsigned expect) {
  const int lane = threadIdx.x & 63;
  const unsigned* p = f + 4 * lane;
  for (;;) {
    unsigned a = __hip_atomic_load(p,     __ATOMIC_RELAXED, __HIP_MEMORY_SCOPE_AGENT);
    unsigned b = __hip_atomic_load(p + 1, __ATOMIC_RELAXED, __HIP_MEMORY_SCOPE_AGENT);
    unsigned c = __hip_atomic_load(p + 2, __ATOMIC_RELAXED, __HIP_MEMORY_SCOPE_AGENT);
    unsigned d = __hip_atomic_load(p + 3, __ATOMIC_RELAXED, __HIP_MEMORY_SCOPE_AGENT);
    if (__ballot((a == expect) && (b == expect) && (c == expect) && (d == expect))
        == 0xFFFFFFFFFFFFFFFFull) break;
  }
}

extern "C" __global__ void __launch_bounds__(256, 1)
gru2_lockstep(const float* __restrict__ x,     // [64][512][512] f32
              const int*   __restrict__ mask,  // [64][512] i32
              const float* __restrict__ W0,    // [512][1536] f32
              const float* __restrict__ U0,
              const float* __restrict__ b0,    // [2][1536]
              const float* __restrict__ W1,
              const float* __restrict__ U1,
              const float* __restrict__ b1,
              float* __restrict__ out,         // [16777216 + 2*32768] f32
              unsigned char* __restrict__ ws)
{
  extern __shared__ unsigned short sm[];
  unsigned short* wt  = sm;                 // [96][520] bf16 transposed weights
  unsigned short* st0 = sm + 96 * 520;      // [16][520] input operand (x or h0n)
  unsigned short* st1 = st0 + 16 * 520;     // [16][520] hidden operand
  float* accs = (float*)(st1 + 16 * 520);   // [4][256]
  unsigned short* pub16 = (unsigned short*)(accs + 1024);  // [2][16][16] publish staging

  unsigned short* h0pub = (unsigned short*)ws;             // [2][64][512] bf16 (masked h0)
  unsigned short* h1pub = (unsigned short*)(ws + 131072);  // [2][64][512] bf16 (masked h1)
  unsigned short* h0n   = (unsigned short*)(ws + 262144);  // [2][64][512] bf16 (UNMASKED h0n)
  unsigned*       flags = (unsigned*)      (ws + 393216);  // [513][256] u32

  const int tid  = threadIdx.x;
  const int wg   = blockIdx.x;
  const int pipe = wg & 1;
  const int idx  = wg >> 1;
  const int mi = idx & 3,  ni = idx >> 2;
  const int r0 = mi * 16,  c0 = ni * 16;
  const int wave = tid >> 6, lane = tid & 63;
  const int quad = lane >> 4, n16 = lane & 15;

  const float* Wm = pipe ? W1 : W0;
  const float* Um = pipe ? U1 : U0;
  const float* bp = pipe ? b1 : b0;
  unsigned short* hpub = pipe ? h1pub : h0pub;

  // ---- one-time: transpose my 48 gate-cols of W and U into LDS bf16 [n][k] ----
  {
    const int col  = tid & 15;
    const int ksub = tid >> 4;
    for (int k0 = 0; k0 < 512; k0 += 16) {
      const int k = k0 + ksub;
      const float* M0 = Wm + (size_t)k * 1536;
      const float* M1 = Um + (size_t)k * 1536;
      #pragma unroll
      for (int g = 0; g < 3; ++g) {
        wt[(g * 16 + col) * 520 + k]      = f2bf(M0[g * 512 + c0 + col]);
        wt[(48 + g * 16 + col) * 520 + k] = f2bf(M1[g * 512 + c0 + col]);
      }
    }
  }
  __syncthreads();

  // wave roles: w0=z (concat x|h), w1=r (concat), w2=ih (x), w3=hh (h)
  const int g  = (wave < 2) ? wave : 2;
  const int np = (wave < 2) ? 2 : 1;

  bfrag_t bw0[16], bw1[16];
  {
    const int mat0 = (wave == 3) ? 1 : 0;
    const int row0 = mat0 * 48 + g * 16 + n16;
    #pragma unroll
    for (int f = 0; f < 16; ++f)
      bw0[f] = *(const bfrag_t*)&wt[row0 * 520 + f * 32 + quad * 8];
    if (np == 2) {
      const int row1 = 48 + g * 16 + n16;
      #pragma unroll
      for (int f = 0; f < 16; ++f)
        bw1[f] = *(const bfrag_t*)&wt[row1 * 520 + f * 32 + quad * 8];
    }
  }

  float bsc;
  {
    const int colg = g * 512 + c0 + n16;
    const float bi = bp[colg];
    const float bh = bp[1536 + colg];
    bsc = (wave < 2) ? (bi + bh) : ((wave == 2) ? bi : bh);
  }

  float hcar = 0.0f;   // fp32 carry of my h element (WG-local!)
  float oprev = 0.0f;
  const int erow = tid >> 4, ecol = tid & 15;
  const int eb = r0 + erow, ec = c0 + ecol;

  for (int s = 0; s <= TT; ++s) {
    const bool actA = (pipe == 0) && (s < TT);
    const bool actB = (pipe == 1) && (s > 0);
    const bool act  = actA || actB;
    const int  t    = pipe ? (s - 1) : s;

    // mask prefetch (regular cached load, overlapped with everything below)
    const int mv = act ? mask[(size_t)eb * 512 + t] : 0;

    // ---- barrier wait (wave 0) overlapped with pipe-A x(s) prestage ----
    if (actA && tid >= 128) {
      const int sm2 = (tid - 128) >> 3;     // 0..15 row
      const int sk2 = (tid & 7) * 64;       // col start
      const float* src = x + (((size_t)(r0 + sm2) * 512 + s) * 512 + sk2);
      uint4* dst = (uint4*)(st0 + sm2 * 520 + sk2);
      #pragma unroll
      for (int c = 0; c < 8; ++c) {
        float4 a = ((const float4*)src)[2 * c];
        float4 b = ((const float4*)src)[2 * c + 1];
        uint4 u;
        u.x = pack2(a.x, a.y);  u.y = pack2(a.z, a.w);
        u.z = pack2(b.x, b.y);  u.w = pack2(b.z, b.w);
        dst[c] = u;
      }
    } else if (wave == 0 && s > 0) {
      spin256(flags + (size_t)(s - 1) * 256, (unsigned)s);
    }
    __syncthreads();

    // ---- stage hidden operand st1 <- hpub (bf16, sc1); pipe B: st0 <- h0n ----
    if (act) {
      const int row = tid >> 4;             // 0..15
      const int cofs = (tid & 15) * 32;     // bf16 elems
      const unsigned short* hsrc = hpub + (size_t)((t + 1) & 1) * 32768 +
                                   (size_t)(r0 + row) * 512 + cofs;
      #pragma unroll
      for (int j = 0; j < 8; ++j) {
        unsigned long long v = ld8(hsrc + j * 4);
        *(unsigned long long*)&st1[row * 520 + cofs + j * 4] = v;
      }
      if (pipe == 1) {
        const unsigned short* nsrc = h0n + (size_t)(t & 1) * 32768 +
                                     (size_t)(r0 + row) * 512 + cofs;
        #pragma unroll
        for (int j = 0; j < 8; ++j) {
          unsigned long long v = ld8(nsrc + j * 4);
          *(unsigned long long*)&st0[row * 520 + cofs + j * 4] = v;
        }
      }
    }
    __syncthreads();

    // ---- MFMA ----
    if (act) {
      f32x4 acc = {bsc, bsc, bsc, bsc};
      const unsigned short* s0 = (wave == 3) ? st1 : st0;
      const int abase = n16 * 520 + quad * 8;
      #pragma unroll
      for (int f = 0; f < 16; ++f) {
        bfrag_t a = *(const bfrag_t*)&s0[abase + f * 32];
        acc = __builtin_amdgcn_mfma_f32_16x16x32_bf16(a, bw0[f], acc, 0, 0, 0);
      }
      if (np == 2) {
        #pragma unroll
        for (int f = 0; f < 16; ++f) {
          bfrag_t a = *(const bfrag_t*)&st1[abase + f * 32];
          acc = __builtin_amdgcn_mfma_f32_16x16x32_bf16(a, bw1[f], acc, 0, 0, 0);
        }
      }
      #pragma unroll
      for (int i = 0; i < 4; ++i)
        accs[wave * 256 + (quad * 4 + i) * 16 + n16] = acc[i];  // row=quad*4+i, col=n16
    }
    __syncthreads();

    // ---- elementwise GRU cell (register h-carry) ----
    if (act) {
      const float zv = sigmoidf_(accs[tid]);
      const float rv = sigmoidf_(accs[256 + tid]);
      const float candv = fast_tanh(accs[512 + tid] + rv * accs[768 + tid]);
      const float hold = hcar;
      const float hn = zv * hold + (1.0f - zv) * candv;
      const bool  m  = mv != 0;
      const float hc = m ? hn : hold;
      hcar = hc;
      pub16[erow * 16 + ecol] = f2bf(hc);
      if (pipe == 0) {
        pub16[256 + erow * 16 + ecol] = f2bf(hn);   // UNMASKED h0n for layer 1
        if (t == TT - 1) out[(size_t)16777216 + (size_t)eb * 512 + ec] = hc;         // h0f
      } else {
        const float ov = m ? hn : oprev;
        oprev = ov;
        out[(size_t)eb * 262144 + (size_t)t * 512 + ec] = ov;                         // output
        if (t == TT - 1) out[(size_t)16777216 + 32768 + (size_t)eb * 512 + ec] = hc;  // h1f
      }
    }
    __syncthreads();

    // ---- publish bf16 tiles (sc1 relaxed 8B stores) ----
    if (act) {
      const int nst = (pipe == 0) ? 128 : 64;
      if (tid < nst) {
        const int v  = tid >> 6;          // 0: masked h, 1: unmasked h0n (pipe A only)
        const int r  = (tid >> 2) & 15;
        const int sg = tid & 3;
        unsigned long long val = *(unsigned long long*)&pub16[v * 256 + r * 16 + sg * 4];
        unsigned short* dst;
        if (pipe == 0) dst = (v ? h0n : h0pub) + (size_t)(t & 1) * 32768;
        else           dst = h1pub + (size_t)(t & 1) * 32768;
        st8(dst + (size_t)(r0 + r) * 512 + c0 + sg * 4, val);
      }
    }
    asm volatile("s_waitcnt vmcnt(0)" ::: "memory");  // publishes complete (MALL)
    __syncthreads();
    if (tid == 0)
      __hip_atomic_store(&flags[(size_t)s * 256 + wg], (unsigned)(s + 1),
                         __ATOMIC_RELAXED, __HIP_MEMORY_SCOPE_AGENT);
  }
}

extern "C" void kernel_launch(void* const* d_in, const int* in_sizes, int n_in,
                              void* d_out, int out_size, void* d_ws, size_t ws_size,
                              hipStream_t stream) {
  (void)in_sizes; (void)n_in; (void)out_size;
  const float* x    = (const float*)d_in[0];
  const int*   mask = (const int*)  d_in[1];
  const float* W0   = (const float*)d_in[2];
  const float* U0   = (const float*)d_in[3];
  const float* b0   = (const float*)d_in[4];
  const float* W1   = (const float*)d_in[5];
  const float* U1   = (const float*)d_in[6];
  const float* b1   = (const float*)d_in[7];
  float* out = (float*)d_out;
  unsigned char* ws = (unsigned char*)d_ws;

  const size_t need = 918528;   // pub buffers + h0n + flags
  const size_t zb = ws_size < need ? ws_size : need;
  hipMemsetAsync(d_ws, 0, zb, stream);

  hipFuncSetAttribute((const void*)gru2_lockstep,
                      hipFuncAttributeMaxDynamicSharedMemorySize, 139264);
  void* args[] = { (void*)&x, (void*)&mask, (void*)&W0, (void*)&U0, (void*)&b0,
                   (void*)&W1, (void*)&U1, (void*)&b1, (void*)&out, (void*)&ws };
  hipLaunchCooperativeKernel((void*)gru2_lockstep, dim3(256), dim3(256),
                             args, 139264, stream);
}